// Round 5
// baseline (412.182 us; speedup 1.0000x reference)
//
#include <hip/hip_runtime.h>
#include <math.h>

#define IMG 401
#define NKP 17
#define NMID 32
#define CCH 150   // coarse channels: 0-16 kp(sig) | 17-50 so | 51-114 mo | 115-148 lo | 149 ss(sig)

// output region element offsets (f32 elements); mid has 64 ch/pixel (4*NUM_EDGES, NUM_EDGES=16)
#define OFF_KP   0ULL
#define OFF_SO   5467234ULL
#define OFF_MID  16401702ULL
#define OFF_LONG 36984230ULL
#define OFF_SS   47918698ULL
// total out_size = 48,240,300 f32 elements

// coarse head outputs in static device memory; fully rewritten every call.
__device__ float g_coarse[2 * 169 * CCH];

__constant__ int TO_KP_C[32] = {1,3,2,4,5,7,9,11,13,15,6,8,10,12,14,16,
                                0,1,0,2,0,5,7,5,11,13,0,6,8,6,12,14};

__device__ __forceinline__ void store2(float* p, float a, float b) {
  *reinterpret_cast<float2*>(p) = make_float2(a, b);   // 8B-aligned by construction
}

// ---------------- kernel 1: heads GEMM (x[338,2048] @ W -> coarse[2,13,13,150]) ----------
__global__ __launch_bounds__(256)
void heads_kernel(const float* __restrict__ x,
                  const float* __restrict__ kp_w, const float* __restrict__ kp_b,
                  const float* __restrict__ so_w, const float* __restrict__ so_b,
                  const float* __restrict__ mo_w, const float* __restrict__ mo_b,
                  const float* __restrict__ lo_w, const float* __restrict__ lo_b,
                  const float* __restrict__ ss_w, const float* __restrict__ ss_b) {
  __shared__ float xs[2048];
  const int pix = blockIdx.x;                 // 0..337  (= n*169 + y*13 + x)
  const float* xr = x + (size_t)pix * 2048;
  for (int t = threadIdx.x; t < 2048; t += 256) xs[t] = xr[t];
  __syncthreads();
  const int c = threadIdx.x;
  if (c >= CCH) return;
  const float* wptr; const float* bptr; int Ch, cc; bool sig = false;
  if (c < 17)       { wptr = kp_w; bptr = kp_b; Ch = 17; cc = c;       sig = true; }
  else if (c < 51)  { wptr = so_w; bptr = so_b; Ch = 34; cc = c - 17; }
  else if (c < 115) { wptr = mo_w; bptr = mo_b; Ch = 64; cc = c - 51; }
  else if (c < 149) { wptr = lo_w; bptr = lo_b; Ch = 34; cc = c - 115; }
  else              { wptr = ss_w; bptr = ss_b; Ch = 1;  cc = 0;       sig = true; }
  float acc = bptr[cc];
  const float* wp = wptr + cc;
  #pragma unroll 8
  for (int k = 0; k < 2048; ++k) acc = fmaf(xs[k], wp[k * Ch], acc);
  if (sig) acc = 1.0f / (1.0f + expf(-acc));
  g_coarse[(size_t)pix * CCH + c] = acc;
}

// ------------- fine-grid index -> coarse cell map (jax.image.resize bilinear, clamped) ----
__device__ __forceinline__ void cmapf(int j, int& i0, int& i1, float& f) {
  const float SC = 13.0f / 401.0f;
  const float C0 = 13.0f / 802.0f - 0.5f;     // (0.5*13/401 - 0.5)
  float s  = fmaf((float)j, SC, C0);
  float fl = floorf(s);
  f = s - fl;
  int a = (int)fl, b = a + 1;
  i0 = a < 0 ? 0 : (a > 12 ? 12 : a);
  i1 = b < 0 ? 0 : (b > 12 ? 12 : b);
}

__device__ __forceinline__ float2 blp(const float2* __restrict__ F,
                                      int y0, int y1, int x0, int x1, float u, float v) {
  float2 c00 = F[y0 * 13 + x0], c01 = F[y0 * 13 + x1];
  float2 c10 = F[y1 * 13 + x0], c11 = F[y1 * 13 + x1];
  float w00 = (1.f - u) * (1.f - v), w01 = u * (1.f - v);
  float w10 = (1.f - u) * v,         w11 = u * v;
  return make_float2(w00 * c00.x + w01 * c01.x + w10 * c10.x + w11 * c11.x,
                     w00 * c00.y + w01 * c01.y + w10 * c10.y + w11 * c11.y);
}

// ----- one bilinear_sampler evaluation: sample resized field F (from 13x13 coarse) at base -----
__device__ __forceinline__ float2 sampleF(const float2* __restrict__ F, float2 base, int w, int h) {
  float vx = base.x, vy = base.y;
  float fx0 = floorf(vx), fy0 = floorf(vy);
  float fx1 = ceilf(vx),  fy1 = ceilf(vy);
  int jx0 = (int)fx0 + w, jx1 = (int)fx1 + w;
  int jy0 = (int)fy0 + h, jy1 = (int)fy1 + h;
  if ((jx0 | jy0) < 0 || jx1 > 400 || jy1 > 400) return make_float2(0.f, 0.f);
  float dx = vx - fx0, dy = vy - fy0;
  int xa0, xa1, xb0, xb1, ya0, ya1, yb0, yb1;
  float fxa, fxb, fya, fyb;
  cmapf(jx0, xa0, xa1, fxa); cmapf(jx1, xb0, xb1, fxb);
  cmapf(jy0, ya0, ya1, fya); cmapf(jy1, yb0, yb1, fyb);
  if (xa0 == xb0 && xa1 == xb1 && ya0 == yb0 && ya1 == yb1) {
    // all four fine corners in one coarse cell: bilerp-of-bilerp == bilerp at averaged fracs
    float u = fxa + dx * (fxb - fxa);
    float v = fya + dy * (fyb - fya);
    return blp(F, ya0, ya1, xa0, xa1, u, v);
  }
  float2 a00 = blp(F, ya0, ya1, xa0, xa1, fxa, fya);   // (y0, x0)
  float2 a01 = blp(F, yb0, yb1, xa0, xa1, fxa, fyb);   // (y1, x0)
  float2 a10 = blp(F, ya0, ya1, xb0, xb1, fxb, fya);   // (y0, x1)
  float2 a11 = blp(F, yb0, yb1, xb0, xb1, fxb, fyb);   // (y1, x1)
  float w00 = (1.f - dx) * (1.f - dy), w01 = (1.f - dx) * dy;
  float w10 = dx * (1.f - dy),         w11 = dx * dy;
  return make_float2(w00 * a00.x + w01 * a01.x + w10 * a10.x + w11 * a11.x,
                     w00 * a00.y + w01 * a01.y + w10 * a10.y + w11 * a11.y);
}

// ---------------- kernel 2: fused resize + refinement + all outputs ----------------------
__global__ __launch_bounds__(256)
void refine_kernel(float* __restrict__ out) {
  __shared__ float2 Sf[NKP][169];
  __shared__ float2 Lf[NKP][169];
  const int n = blockIdx.z;
  const float* cb = g_coarse + (size_t)n * 169 * CCH;
  const int tid = threadIdx.y * 16 + threadIdx.x;
  for (int t = tid; t < NKP * 169; t += 256) {
    int k = t / 169, p = t - k * 169;
    int base = p * CCH;
    Sf[k][p] = make_float2(cb[base + 17 + 2 * k],  cb[base + 18 + 2 * k]);
    Lf[k][p] = make_float2(cb[base + 115 + 2 * k], cb[base + 116 + 2 * k]);
  }
  __syncthreads();
  const int w = blockIdx.x * 16 + threadIdx.x;
  const int h = blockIdx.y * 16 + threadIdx.y;
  if (w >= IMG || h >= IMG) return;

  int px0, px1, py0, py1; float pfx, pfy;
  cmapf(w, px0, px1, pfx);
  cmapf(h, py0, py1, pfy);
  const size_t pix = ((size_t)n * IMG + h) * IMG + w;

  const float* c00 = cb + (py0 * 13 + px0) * CCH;
  const float* c01 = cb + (py0 * 13 + px1) * CCH;
  const float* c10 = cb + (py1 * 13 + px0) * CCH;
  const float* c11 = cb + (py1 * 13 + px1) * CCH;
  const float q00 = (1.f - pfx) * (1.f - pfy), q01 = pfx * (1.f - pfy);
  const float q10 = (1.f - pfx) * pfy,         q11 = pfx * pfy;

  // kp (17, sigmoid already applied in coarse)
  float* okp = out + OFF_KP + pix * 17;
  #pragma unroll
  for (int c = 0; c < 17; ++c)
    okp[c] = q00 * c00[c] + q01 * c01[c] + q10 * c10[c] + q11 * c11[c];
  // ss
  out[OFF_SS + pix] = q00 * c00[149] + q01 * c01[149] + q10 * c10[149] + q11 * c11[149];

  // so + long
  float* oso = out + OFF_SO + pix * 34;
  float* olg = out + OFF_LONG + pix * 34;
  for (int k = 0; k < NKP; ++k) {
    const float2* S = Sf[k];
    const float2* L = Lf[k];
    float2 sv = blp(S, py0, py1, px0, px1, pfx, pfy);
    store2(oso + 2 * k, sv.x, sv.y);
    float2 b = blp(L, py0, py1, px0, px1, pfx, pfy);
    float2 d;
    d = sampleF(L, b, w, h); b.x += d.x; b.y += d.y;
    d = sampleF(L, b, w, h); b.x += d.x; b.y += d.y;
    d = sampleF(S, b, w, h); b.x += d.x; b.y += d.y;
    d = sampleF(S, b, w, h); b.x += d.x; b.y += d.y;
    store2(olg + 2 * k, b.x, b.y);
  }

  // mid: 32 groups, 64 channels per pixel
  float* omd = out + OFF_MID + pix * 64;
  for (int g = 0; g < NMID; ++g) {
    int ch = 51 + 2 * g;
    float bx = q00 * c00[ch]     + q01 * c01[ch]     + q10 * c10[ch]     + q11 * c11[ch];
    float by = q00 * c00[ch + 1] + q01 * c01[ch + 1] + q10 * c10[ch + 1] + q11 * c11[ch + 1];
    const float2* S = Sf[TO_KP_C[g]];
    float2 b = make_float2(bx, by);
    float2 d;
    d = sampleF(S, b, w, h); b.x += d.x; b.y += d.y;
    d = sampleF(S, b, w, h); b.x += d.x; b.y += d.y;
    store2(omd + 2 * g, b.x, b.y);
  }
}

extern "C" void kernel_launch(void* const* d_in, const int* in_sizes, int n_in,
                              void* d_out, int out_size, void* d_ws, size_t ws_size,
                              hipStream_t stream) {
  const float* x    = (const float*)d_in[0];
  const float* kp_w = (const float*)d_in[1];
  const float* kp_b = (const float*)d_in[2];
  const float* so_w = (const float*)d_in[3];
  const float* so_b = (const float*)d_in[4];
  const float* mo_w = (const float*)d_in[5];
  const float* mo_b = (const float*)d_in[6];
  const float* lo_w = (const float*)d_in[7];
  const float* lo_b = (const float*)d_in[8];
  const float* ss_w = (const float*)d_in[9];
  const float* ss_b = (const float*)d_in[10];
  float* out = (float*)d_out;

  heads_kernel<<<dim3(338), dim3(256), 0, stream>>>(x, kp_w, kp_b, so_w, so_b,
                                                    mo_w, mo_b, lo_w, lo_b,
                                                    ss_w, ss_b);
  dim3 grid(26, 26, 2), block(16, 16, 1);
  refine_kernel<<<grid, block, 0, stream>>>(out);
}